// Round 1
// baseline (249.033 us; speedup 1.0000x reference)
//
#include <hip/hip_runtime.h>
#include <hip/hip_bf16.h>
#include <cmath>

// ---- model dims ----
#define F_   32
#define V_   1000
#define D_   64
#define B_   8192
#define IN_RAW  2544      // F*D + F*(F-1)/2 = 2048 + 496
#define IN_PAD  2560      // padded so BK=32 divides
#define H1_  1024
#define H2_  512
#define OUT_RAW 1000
#define OUT_PAD 1024

typedef __attribute__((ext_vector_type(4))) float f32x4;
typedef __attribute__((ext_vector_type(8))) __bf16 bf16x8;

typedef const __attribute__((address_space(1))) void* gptr_t;
typedef __attribute__((address_space(3))) void* lptr_t;

__device__ __forceinline__ void gload_lds16(const void* g, void* l) {
  // async global->LDS, 16B per lane; LDS dest = wave-uniform base + lane*16
  __builtin_amdgcn_global_load_lds((gptr_t)g, (lptr_t)l, 16, 0, 0);
}

// ---------------------------------------------------------------------------
// Kernel 1: embedding gather + pairwise interactions -> h (bf16, [B][IN_PAD])
// one block per batch row
// ---------------------------------------------------------------------------
__global__ __launch_bounds__(256)
void interact_kernel(const int* __restrict__ x, const float* __restrict__ emb,
                     __hip_bfloat16* __restrict__ h)
{
  __shared__ int xs[F_];
  __shared__ float e[F_][D_ + 1];   // +1 pad: bank spread for dot-product reads
  const int b = blockIdx.x;
  const int tid = threadIdx.x;

  if (tid < F_) xs[tid] = x[b * F_ + tid];
  __syncthreads();

  const size_t hrow = (size_t)b * IN_PAD;
#pragma unroll
  for (int i = 0; i < 8; ++i) {
    int idx = tid + i * 256;          // 0..2047
    int f = idx >> 6, d = idx & 63;
    float v = emb[((size_t)f * V_ + xs[f]) * D_ + d];
    e[f][d] = v;
    h[hrow + idx] = __float2bfloat16(v);
  }
  __syncthreads();

  for (int p = tid; p < 496; p += 256) {
    int i = 0, pp = p;
    while (pp >= 31 - i) { pp -= 31 - i; ++i; }
    int j = i + 1 + pp;
    float s = 0.f;
#pragma unroll
    for (int d = 0; d < D_; ++d) s += e[i][d] * e[j][d];
    h[hrow + 2048 + p] = __float2bfloat16(s);
  }
  if (tid < IN_PAD - IN_RAW) h[hrow + IN_RAW + tid] = __float2bfloat16(0.f);
}

// ---------------------------------------------------------------------------
// Kernel 2: fp32 W[K][N] -> bf16 Wt[Npad][Kpad] (transposed, zero-padded)
// block dim3(32,8); grid (Kpad/32, Npad/32)
// ---------------------------------------------------------------------------
__global__ __launch_bounds__(256)
void convert_transpose(const float* __restrict__ W, __hip_bfloat16* __restrict__ Wt,
                       int K, int N, int Kpad, int Npad)
{
  __shared__ float t[32][33];
  const int k0 = blockIdx.x * 32, n0 = blockIdx.y * 32;
  const int tx = threadIdx.x, ty = threadIdx.y;
#pragma unroll
  for (int i = 0; i < 4; ++i) {
    int r = ty + i * 8;
    int k = k0 + r, n = n0 + tx;
    t[r][tx] = (k < K && n < N) ? W[(size_t)k * N + n] : 0.f;
  }
  __syncthreads();
#pragma unroll
  for (int i = 0; i < 4; ++i) {
    int r = ty + i * 8;
    Wt[(size_t)(n0 + r) * Kpad + (k0 + tx)] = __float2bfloat16(t[tx][r]);
  }
}

// ---------------------------------------------------------------------------
// Kernel 3: C = A[M][K] * Bt[N][K]^T, m97-structure 128x128 tile, BK=32
// EPI 0: relu(v+bias) -> bf16 C[M][N]
// EPI 1: sigmoid(v+bias) -> fp32 C[M][Nreal], cols >= Nreal masked
// ---------------------------------------------------------------------------
template <int EPI>
__global__ __launch_bounds__(256)
void gemm_bt(const __hip_bfloat16* __restrict__ A,
             const __hip_bfloat16* __restrict__ Bt,
             const float* __restrict__ bias,
             void* __restrict__ Cout,
             int M, int N, int K, int Nreal)
{
  __shared__ __align__(16) __hip_bfloat16 ldsA[128 * 32];
  __shared__ __align__(16) __hip_bfloat16 ldsB[128 * 32];

  const int tid  = threadIdx.x;
  const int wid  = tid >> 6;
  const int lane = tid & 63;
  const int wr = wid >> 1, wc = wid & 1;       // 2x2 waves -> 64x64 each
  const int lr = lane & 15;
  const int lk = (lane >> 4) * 8;
  const long rowBase = (long)blockIdx.x * 128;
  const long colBase = (long)blockIdx.y * 128;

  f32x4 acc[4][4] = {};

  // staging addresses: linear [128][32] bf16 = 8 KiB per operand, 2 issues each
  const int eoff0 = tid * 8;                 // issue 0 element offset
  const int r0 = eoff0 >> 5, c0 = eoff0 & 31;
  const int eoff1 = 2048 + tid * 8;          // issue 1
  const int r1 = eoff1 >> 5, c1 = eoff1 & 31;

  for (int k0 = 0; k0 < K; k0 += 32) {
    gload_lds16(A  + (rowBase + r0) * (long)K + k0 + c0, (char*)ldsA + wid * 1024);
    gload_lds16(A  + (rowBase + r1) * (long)K + k0 + c1, (char*)ldsA + 4096 + wid * 1024);
    gload_lds16(Bt + (colBase + r0) * (long)K + k0 + c0, (char*)ldsB + wid * 1024);
    gload_lds16(Bt + (colBase + r1) * (long)K + k0 + c1, (char*)ldsB + 4096 + wid * 1024);
    asm volatile("s_waitcnt vmcnt(0)" ::: "memory");
    __syncthreads();

    bf16x8 af[4], bfr[4];
#pragma unroll
    for (int m = 0; m < 4; ++m)
      af[m] = *reinterpret_cast<const bf16x8*>(&ldsA[(wr * 64 + m * 16 + lr) * 32 + lk]);
#pragma unroll
    for (int n = 0; n < 4; ++n)
      bfr[n] = *reinterpret_cast<const bf16x8*>(&ldsB[(wc * 64 + n * 16 + lr) * 32 + lk]);
#pragma unroll
    for (int m = 0; m < 4; ++m)
#pragma unroll
      for (int n = 0; n < 4; ++n)
        acc[m][n] = __builtin_amdgcn_mfma_f32_16x16x32_bf16(af[m], bfr[n], acc[m][n], 0, 0, 0);
    __syncthreads();
  }

  // epilogue: C/D layout col = lane&15, row = (lane>>4)*4 + reg
#pragma unroll
  for (int m = 0; m < 4; ++m) {
    const long row0 = rowBase + wr * 64 + m * 16 + (lane >> 4) * 4;
#pragma unroll
    for (int n = 0; n < 4; ++n) {
      const int col = (int)colBase + wc * 64 + n * 16 + lr;
      const float bv = (col < Nreal) ? bias[col] : 0.f;
#pragma unroll
      for (int j = 0; j < 4; ++j) {
        float v = acc[m][n][j] + bv;
        const long row = row0 + j;
        if (EPI == 0) {
          v = fmaxf(v, 0.f);
          ((__hip_bfloat16*)Cout)[row * N + col] = __float2bfloat16(v);
        } else {
          if (col < Nreal)
            ((float*)Cout)[row * Nreal + col] = 1.f / (1.f + expf(-v));
        }
      }
    }
  }
}

// ---------------------------------------------------------------------------
extern "C" void kernel_launch(void* const* d_in, const int* in_sizes, int n_in,
                              void* d_out, int out_size, void* d_ws, size_t ws_size,
                              hipStream_t stream)
{
  const int*   x   = (const int*)  d_in[0];
  const float* emb = (const float*)d_in[1];
  const float* W1  = (const float*)d_in[2];
  const float* b1  = (const float*)d_in[3];
  const float* W2  = (const float*)d_in[4];
  const float* b2  = (const float*)d_in[5];
  const float* W3  = (const float*)d_in[6];
  const float* b3  = (const float*)d_in[7];
  float* out = (float*)d_out;

  char* ws = (char*)d_ws;
  size_t off = 0;
  auto alloc = [&](size_t bytes) { size_t o = off; off = (off + bytes + 255) & ~255ULL; return o; };
  __hip_bfloat16* h   = (__hip_bfloat16*)(ws + alloc((size_t)B_ * IN_PAD * 2));
  __hip_bfloat16* w1t = (__hip_bfloat16*)(ws + alloc((size_t)H1_ * IN_PAD * 2));
  __hip_bfloat16* w2t = (__hip_bfloat16*)(ws + alloc((size_t)H2_ * H1_ * 2));
  __hip_bfloat16* w3t = (__hip_bfloat16*)(ws + alloc((size_t)OUT_PAD * H2_ * 2));
  __hip_bfloat16* h1  = (__hip_bfloat16*)(ws + alloc((size_t)B_ * H1_ * 2));
  __hip_bfloat16* h2  = (__hip_bfloat16*)(ws + alloc((size_t)B_ * H2_ * 2));

  dim3 tb(32, 8);
  // W1: [2544][1024] -> w1t [1024][2560]
  convert_transpose<<<dim3(IN_PAD / 32, H1_ / 32), tb, 0, stream>>>(W1, w1t, IN_RAW, H1_, IN_PAD, H1_);
  // W2: [1024][512] -> w2t [512][1024]
  convert_transpose<<<dim3(H1_ / 32, H2_ / 32), tb, 0, stream>>>(W2, w2t, H1_, H2_, H1_, H2_);
  // W3: [512][1000] -> w3t [1024][512]
  convert_transpose<<<dim3(H2_ / 32, OUT_PAD / 32), tb, 0, stream>>>(W3, w3t, H2_, OUT_RAW, H2_, OUT_PAD);

  interact_kernel<<<B_, 256, 0, stream>>>(x, emb, h);

  // L1: h[8192][2560] @ W1 -> h1 bf16 [8192][1024], relu
  gemm_bt<0><<<dim3(B_ / 128, H1_ / 128), 256, 0, stream>>>(h, w1t, b1, h1, B_, H1_, IN_PAD, H1_);
  // L2: h1 @ W2 -> h2 bf16 [8192][512], relu
  gemm_bt<0><<<dim3(B_ / 128, H2_ / 128), 256, 0, stream>>>(h1, w2t, b2, h2, B_, H2_, H1_, H2_);
  // L3: h2 @ W3 -> out fp32 [8192][1000], sigmoid, masked to 1000 cols
  gemm_bt<1><<<dim3(B_ / 128, OUT_PAD / 128), 256, 0, stream>>>(h2, w3t, b3, out, B_, OUT_PAD, H2_, OUT_RAW);
}

// Round 2
// 192.240 us; speedup vs baseline: 1.2954x; 1.2954x over previous
//
#include <hip/hip_runtime.h>
#include <hip/hip_bf16.h>
#include <cmath>

// ---- model dims ----
#define F_   32
#define V_   1000
#define D_   64
#define B_   8192
#define IN_RAW  2544      // F*D + F*(F-1)/2 = 2048 + 496
#define IN_PAD  2560      // padded so BK=64 divides (40 tiles)
#define H1_  1024
#define H2_  512
#define OUT_RAW 1000
#define OUT_PAD 1024

typedef __attribute__((ext_vector_type(4))) float f32x4;
typedef __attribute__((ext_vector_type(8))) __bf16 bf16x8;

typedef const __attribute__((address_space(1))) void* gptr_t;
typedef __attribute__((address_space(3))) void* lptr_t;

__device__ __forceinline__ void gload_lds16(const void* g, void* l) {
  // async global->LDS, 16B per lane; LDS dest = wave-uniform base + lane*16
  __builtin_amdgcn_global_load_lds((gptr_t)g, (lptr_t)l, 16, 0, 0);
}

// ---------------------------------------------------------------------------
// Kernel 1: embedding gather + MFMA gram interactions -> h (bf16, [B][IN_PAD])
// 4 batches per block, one wave each. e tile in LDS, XOR-swizzled (chunk^row&7)
// ---------------------------------------------------------------------------
__global__ __launch_bounds__(256)
void interact_kernel(const int* __restrict__ x, const float* __restrict__ emb,
                     __hip_bfloat16* __restrict__ h)
{
  __shared__ __align__(16) __hip_bfloat16 e4[4][32 * 64];   // 16 KB
  const int wid  = threadIdx.x >> 6;
  const int lane = threadIdx.x & 63;
  const int b = blockIdx.x * 4 + wid;
  const int* xb = x + b * F_;
  const size_t hrow = (size_t)b * IN_PAD;

  // gather: per iter, 4 rows x 16 lanes x float4 (coalesced 256B/row)
#pragma unroll
  for (int it = 0; it < 8; ++it) {
    const int r = it * 4 + (lane >> 4);
    const int d = (lane & 15) * 4;
    const int idx = xb[r];
    const float4 v = *reinterpret_cast<const float4*>(
        &emb[((size_t)r * V_ + idx) * D_ + d]);
    __hip_bfloat16 t[4];
    t[0] = __float2bfloat16(v.x); t[1] = __float2bfloat16(v.y);
    t[2] = __float2bfloat16(v.z); t[3] = __float2bfloat16(v.w);
    const ushort4 pk = *reinterpret_cast<const ushort4*>(t);
    *reinterpret_cast<ushort4*>(&h[hrow + r * 64 + d]) = pk;       // h e-part
    const int ch = (d >> 3) ^ (r & 7);                             // swizzled LDS
    *reinterpret_cast<ushort4*>(&e4[wid][r * 64 + ch * 8 + (d & 7)]) = pk;
  }
  __syncthreads();

  // gram = e @ e^T via 16x16x32 MFMA: 2x2 tiles x 2 k-steps; B-frag == A-frag
  f32x4 g[2][2] = {};
#pragma unroll
  for (int kk = 0; kk < 2; ++kk) {
    bf16x8 fa[2];
#pragma unroll
    for (int t = 0; t < 2; ++t) {
      const int r = t * 16 + (lane & 15);
      const int ch = (kk * 4 + (lane >> 4)) ^ (r & 7);
      fa[t] = *reinterpret_cast<const bf16x8*>(&e4[wid][r * 64 + ch * 8]);
    }
#pragma unroll
    for (int ti = 0; ti < 2; ++ti)
#pragma unroll
      for (int tj = 0; tj < 2; ++tj)
        g[ti][tj] = __builtin_amdgcn_mfma_f32_16x16x32_bf16(fa[ti], fa[tj], g[ti][tj], 0, 0, 0);
  }

  // cross terms: C/D layout col=lane&15, row=(lane>>4)*4+reg; keep i<j
#pragma unroll
  for (int ti = 0; ti < 2; ++ti)
#pragma unroll
    for (int tj = 0; tj < 2; ++tj) {
      const int jj = tj * 16 + (lane & 15);
#pragma unroll
      for (int q = 0; q < 4; ++q) {
        const int i = ti * 16 + (lane >> 4) * 4 + q;
        if (i < jj) {
          const int p = i * 31 - (i * (i - 1)) / 2 + (jj - i - 1);
          h[hrow + 2048 + p] = __float2bfloat16(g[ti][tj][q]);
        }
      }
    }
  if (lane < IN_PAD - IN_RAW) h[hrow + IN_RAW + lane] = __float2bfloat16(0.f);
}

// ---------------------------------------------------------------------------
// Kernel 2: fp32 W[K][N] -> bf16 Wt[Npad][Kpad] (transposed, zero-padded)
// ---------------------------------------------------------------------------
__global__ __launch_bounds__(256)
void convert_transpose(const float* __restrict__ W, __hip_bfloat16* __restrict__ Wt,
                       int K, int N, int Kpad, int Npad)
{
  __shared__ float t[32][33];
  const int k0 = blockIdx.x * 32, n0 = blockIdx.y * 32;
  const int tx = threadIdx.x, ty = threadIdx.y;
#pragma unroll
  for (int i = 0; i < 4; ++i) {
    int r = ty + i * 8;
    int k = k0 + r, n = n0 + tx;
    t[r][tx] = (k < K && n < N) ? W[(size_t)k * N + n] : 0.f;
  }
  __syncthreads();
#pragma unroll
  for (int i = 0; i < 4; ++i) {
    int r = ty + i * 8;
    Wt[(size_t)(n0 + r) * Kpad + (k0 + tx)] = __float2bfloat16(t[tx][r]);
  }
}

// ---------------------------------------------------------------------------
// Kernel 3: C = A[M][K] * Bt[N][K]^T, 128x128 tile, BK=64, double-buffered LDS,
// prefetch-before-compute (T3-minimal), XOR-swizzled LDS (conflict-free reads).
// ---------------------------------------------------------------------------
template <int EPI>
__global__ __launch_bounds__(256)
void gemm_bt(const __hip_bfloat16* __restrict__ A,
             const __hip_bfloat16* __restrict__ Bt,
             const float* __restrict__ bias,
             void* __restrict__ Cout,
             int M, int N, int K, int Nreal)
{
  __shared__ __align__(16) __hip_bfloat16 lds[2][2][128 * 64];  // 64 KB

  const int tid  = threadIdx.x;
  const int wid  = tid >> 6;
  const int lane = tid & 63;
  const int wr = wid >> 1, wc = wid & 1;
  const int lr = lane & 15;
  const int lhi = lane >> 4;
  const long rowBase = (long)blockIdx.x * 128;
  const long colBase = (long)blockIdx.y * 128;

  f32x4 acc[4][4] = {};

  // staging: 16KB/operand/tile = 4 issues x 4KB; linear LDS dest,
  // pre-swizzled global source chunk: c = (tid&7) ^ ((tid>>3)&7)
  const int srow = tid >> 3;
  const long scol = (long)(((tid & 7) ^ (srow & 7)) * 8);
  const long aBase = (rowBase + srow) * (long)K + scol;
  const long bBase = (colBase + srow) * (long)K + scol;

  const int NT = K >> 6;

  auto STAGE = [&](int buf, int t) {
    const long k0 = (long)t * 64;
    char* la = (char*)&lds[buf][0][0] + wid * 1024;
    char* lb = (char*)&lds[buf][1][0] + wid * 1024;
#pragma unroll
    for (int j = 0; j < 4; ++j) {
      gload_lds16(A  + aBase + (long)j * 32 * K + k0, la + j * 4096);
      gload_lds16(Bt + bBase + (long)j * 32 * K + k0, lb + j * 4096);
    }
  };

  STAGE(0, 0);
  __syncthreads();

  int cur = 0;
  for (int t = 0; t < NT; ++t) {
    if (t + 1 < NT) STAGE(cur ^ 1, t + 1);

    const __hip_bfloat16* la = &lds[cur][0][0];
    const __hip_bfloat16* lb = &lds[cur][1][0];
#pragma unroll
    for (int kk = 0; kk < 2; ++kk) {
      const int ch = ((kk * 4 + lhi) ^ (lane & 7)) * 8;  // rows step by 16 -> row&7 == lane&7
      bf16x8 af[4], bfv[4];
#pragma unroll
      for (int m = 0; m < 4; ++m)
        af[m] = *reinterpret_cast<const bf16x8*>(&la[(wr * 64 + m * 16 + lr) * 64 + ch]);
#pragma unroll
      for (int n = 0; n < 4; ++n)
        bfv[n] = *reinterpret_cast<const bf16x8*>(&lb[(wc * 64 + n * 16 + lr) * 64 + ch]);
#pragma unroll
      for (int m = 0; m < 4; ++m)
#pragma unroll
        for (int n = 0; n < 4; ++n)
          acc[m][n] = __builtin_amdgcn_mfma_f32_16x16x32_bf16(af[m], bfv[n], acc[m][n], 0, 0, 0);
    }
    __syncthreads();   // vmcnt(0)+lgkmcnt(0) drain: prefetch landed, safe to swap
    cur ^= 1;
  }

  // epilogue: C/D layout col = lane&15, row = (lane>>4)*4 + reg
#pragma unroll
  for (int m = 0; m < 4; ++m) {
    const long row0 = rowBase + wr * 64 + m * 16 + lhi * 4;
#pragma unroll
    for (int n = 0; n < 4; ++n) {
      const int col = (int)colBase + wc * 64 + n * 16 + lr;
      const float bv = (col < Nreal) ? bias[col] : 0.f;
#pragma unroll
      for (int j = 0; j < 4; ++j) {
        float v = acc[m][n][j] + bv;
        const long row = row0 + j;
        if (EPI == 0) {
          v = fmaxf(v, 0.f);
          ((__hip_bfloat16*)Cout)[row * N + col] = __float2bfloat16(v);
        } else {
          if (col < Nreal)
            ((float*)Cout)[row * Nreal + col] = 1.f / (1.f + expf(-v));
        }
      }
    }
  }
}

// ---------------------------------------------------------------------------
extern "C" void kernel_launch(void* const* d_in, const int* in_sizes, int n_in,
                              void* d_out, int out_size, void* d_ws, size_t ws_size,
                              hipStream_t stream)
{
  const int*   x   = (const int*)  d_in[0];
  const float* emb = (const float*)d_in[1];
  const float* W1  = (const float*)d_in[2];
  const float* b1  = (const float*)d_in[3];
  const float* W2  = (const float*)d_in[4];
  const float* b2  = (const float*)d_in[5];
  const float* W3  = (const float*)d_in[6];
  const float* b3  = (const float*)d_in[7];
  float* out = (float*)d_out;

  char* ws = (char*)d_ws;
  size_t off = 0;
  auto alloc = [&](size_t bytes) { size_t o = off; off = (off + bytes + 255) & ~255ULL; return o; };
  __hip_bfloat16* h   = (__hip_bfloat16*)(ws + alloc((size_t)B_ * IN_PAD * 2));
  __hip_bfloat16* w1t = (__hip_bfloat16*)(ws + alloc((size_t)H1_ * IN_PAD * 2));
  __hip_bfloat16* w2t = (__hip_bfloat16*)(ws + alloc((size_t)H2_ * H1_ * 2));
  __hip_bfloat16* w3t = (__hip_bfloat16*)(ws + alloc((size_t)OUT_PAD * H2_ * 2));
  __hip_bfloat16* h1  = (__hip_bfloat16*)(ws + alloc((size_t)B_ * H1_ * 2));
  __hip_bfloat16* h2  = (__hip_bfloat16*)(ws + alloc((size_t)B_ * H2_ * 2));

  dim3 tb(32, 8);
  convert_transpose<<<dim3(IN_PAD / 32, H1_ / 32), tb, 0, stream>>>(W1, w1t, IN_RAW, H1_, IN_PAD, H1_);
  convert_transpose<<<dim3(H1_ / 32, H2_ / 32), tb, 0, stream>>>(W2, w2t, H1_, H2_, H1_, H2_);
  convert_transpose<<<dim3(H2_ / 32, OUT_PAD / 32), tb, 0, stream>>>(W3, w3t, H2_, OUT_RAW, H2_, OUT_PAD);

  interact_kernel<<<B_ / 4, 256, 0, stream>>>(x, emb, h);

  gemm_bt<0><<<dim3(B_ / 128, H1_ / 128), 256, 0, stream>>>(h, w1t, b1, h1, B_, H1_, IN_PAD, H1_);
  gemm_bt<0><<<dim3(B_ / 128, H2_ / 128), 256, 0, stream>>>(h1, w2t, b2, h2, B_, H2_, H1_, H2_);
  gemm_bt<1><<<dim3(B_ / 128, OUT_PAD / 128), 256, 0, stream>>>(h2, w3t, b3, out, B_, OUT_PAD, H2_, OUT_RAW);
}

// Round 3
// 191.160 us; speedup vs baseline: 1.3027x; 1.0056x over previous
//
#include <hip/hip_runtime.h>
#include <hip/hip_bf16.h>
#include <cmath>

// ---- model dims ----
#define F_   32
#define V_   1000
#define D_   64
#define B_   8192
#define IN_RAW  2544      // F*D + F*(F-1)/2 = 2048 + 496
#define IN_PAD  2560
#define H1_  1024
#define H2_  512
#define OUT_RAW 1000
#define OUT_PAD 1024

typedef __attribute__((ext_vector_type(4))) float f32x4;
typedef __attribute__((ext_vector_type(8))) __bf16 bf16x8;

typedef const __attribute__((address_space(1))) void* gptr_t;
typedef __attribute__((address_space(3))) void* lptr_t;

__device__ __forceinline__ void gload_lds16(const void* g, void* l) {
  __builtin_amdgcn_global_load_lds((gptr_t)g, (lptr_t)l, 16, 0, 0);
}

#define MF(a, b, c) __builtin_amdgcn_mfma_f32_16x16x32_bf16((a), (b), (c), 0, 0, 0)
#define SBAR asm volatile("s_barrier" ::: "memory")

// ---------------------------------------------------------------------------
// prep kernel: fuses 3 weight transposes + embedding gather/interaction.
//   blocks [0,2560)     : W1 [2544][1024] -> w1t [1024][2560]
//   blocks [2560,3072)  : W2 [1024][512]  -> w2t [512][1024]
//   blocks [3072,3584)  : W3 [512][1000]  -> w3t [1024][512]
//   blocks [3584,5632)  : interact, 4 batches/block (1 wave each)
// ---------------------------------------------------------------------------
__global__ __launch_bounds__(256)
void prep_kernel(const int* __restrict__ x, const float* __restrict__ emb,
                 const float* __restrict__ W1, const float* __restrict__ W2,
                 const float* __restrict__ W3,
                 __hip_bfloat16* __restrict__ h, __hip_bfloat16* __restrict__ w1t,
                 __hip_bfloat16* __restrict__ w2t, __hip_bfloat16* __restrict__ w3t)
{
  __shared__ __align__(16) char smem[16384];
  const int bid = blockIdx.x;
  const int tid = threadIdx.x;

  if (bid < 3584) {
    const float* W; __hip_bfloat16* Wt; int K, N, Kpad, kb, nb;
    if (bid < 2560)      { W = W1; Wt = w1t; K = IN_RAW; N = H1_;     Kpad = IN_PAD; kb = bid % 80; nb = bid / 80; }
    else if (bid < 3072) { int r = bid - 2560; W = W2; Wt = w2t; K = H1_; N = H2_;   Kpad = H1_;   kb = r % 32;  nb = r / 32; }
    else                 { int r = bid - 3072; W = W3; Wt = w3t; K = H2_; N = OUT_RAW; Kpad = H2_; kb = r % 16;  nb = r / 16; }
    float (*t)[33] = (float(*)[33])smem;
    const int k0 = kb * 32, n0 = nb * 32;
    const int tx = tid & 31, ty = tid >> 5;
#pragma unroll
    for (int i = 0; i < 4; ++i) {
      int r = ty + i * 8;
      int k = k0 + r, n = n0 + tx;
      t[r][tx] = (k < K && n < N) ? W[(size_t)k * N + n] : 0.f;
    }
    __syncthreads();
#pragma unroll
    for (int i = 0; i < 4; ++i) {
      int r = ty + i * 8;
      Wt[(size_t)(n0 + r) * Kpad + (k0 + tx)] = __float2bfloat16(t[tx][r]);
    }
  } else {
    // ---- interact: gather + MFMA gram ----
    __hip_bfloat16 (*e4)[2048] = (__hip_bfloat16(*)[2048])smem;   // [4][32*64]
    const int wid  = tid >> 6;
    const int lane = tid & 63;
    const int b = (bid - 3584) * 4 + wid;
    const int* xb = x + b * F_;
    const size_t hrow = (size_t)b * IN_PAD;

#pragma unroll
    for (int it = 0; it < 8; ++it) {
      const int r = it * 4 + (lane >> 4);
      const int d = (lane & 15) * 4;
      const int idx = xb[r];
      const float4 v = *reinterpret_cast<const float4*>(
          &emb[((size_t)r * V_ + idx) * D_ + d]);
      __hip_bfloat16 tb[4];
      tb[0] = __float2bfloat16(v.x); tb[1] = __float2bfloat16(v.y);
      tb[2] = __float2bfloat16(v.z); tb[3] = __float2bfloat16(v.w);
      const ushort4 pk = *reinterpret_cast<const ushort4*>(tb);
      *reinterpret_cast<ushort4*>(&h[hrow + r * 64 + d]) = pk;
      const int ch = (d >> 3) ^ (r & 7);
      *reinterpret_cast<ushort4*>(&e4[wid][r * 64 + ch * 8 + (d & 7)]) = pk;
    }
    __syncthreads();

    f32x4 g[2][2] = {};
#pragma unroll
    for (int kk = 0; kk < 2; ++kk) {
      bf16x8 fa[2];
#pragma unroll
      for (int t2 = 0; t2 < 2; ++t2) {
        const int r = t2 * 16 + (lane & 15);
        const int ch = (kk * 4 + (lane >> 4)) ^ (r & 7);
        fa[t2] = *reinterpret_cast<const bf16x8*>(&e4[wid][r * 64 + ch * 8]);
      }
#pragma unroll
      for (int ti = 0; ti < 2; ++ti)
#pragma unroll
        for (int tj = 0; tj < 2; ++tj)
          g[ti][tj] = MF(fa[ti], fa[tj], g[ti][tj]);
    }

#pragma unroll
    for (int ti = 0; ti < 2; ++ti)
#pragma unroll
      for (int tj = 0; tj < 2; ++tj) {
        const int jj = tj * 16 + (lane & 15);
#pragma unroll
        for (int q = 0; q < 4; ++q) {
          const int i = ti * 16 + (lane >> 4) * 4 + q;
          if (i < jj) {
            const int p = i * 31 - (i * (i - 1)) / 2 + (jj - i - 1);
            h[hrow + 2048 + p] = __float2bfloat16(g[ti][tj][q]);
          }
        }
      }
    if (lane < IN_PAD - IN_RAW) h[hrow + IN_RAW + lane] = __float2bfloat16(0.f);
  }
}

// ---------------------------------------------------------------------------
// gemm8ph: C = A[M][K] * Bt[N][K]^T. BM=256, BN=128, BK=64. 512 thr, 8 waves
// (4M x 2N, per-wave 64x64). 3-buffer LDS rotation (144 KB): compute tile t
// from buf t%3 while staging tile t+2 into buf (t+2)%3. Counted vmcnt(6) +
// one raw s_barrier per K-tile is the only correctness sync; per-phase raw
// barriers + setprio create the wave role-split (T3/T4/T5). T2 XOR swizzle
// via pre-swizzled global source (chunk ^= row&7). Grid: 1-D, XCD-swizzled.
// ---------------------------------------------------------------------------
template <int EPI>
__global__ __launch_bounds__(512, 2)
void gemm8ph(const __hip_bfloat16* __restrict__ A,
             const __hip_bfloat16* __restrict__ Bt,
             const float* __restrict__ bias,
             void* __restrict__ Cout,
             int M, int N, int K, int Nreal)
{
  __shared__ __align__(16) __hip_bfloat16 lds[3][(256 + 128) * 64];  // 144 KB

  const int tid  = threadIdx.x;
  const int wid  = tid >> 6;
  const int lane = tid & 63;
  const int wr = wid >> 1;        // 0..3 (M)
  const int wc = wid & 1;         // 0..1 (N)
  const int lr = lane & 15;
  const int lhi = lane >> 4;
  const int l7 = lane & 7;

  // XCD-aware bijective swizzle (nblk % 8 == 0): same-XCD blocks share A-panels
  const int nCol = N >> 7;
  const int nblk = gridDim.x;
  const int swz = (blockIdx.x & 7) * (nblk >> 3) + (blockIdx.x >> 3);
  const long rowBase = (long)(swz / nCol) * 256;
  const long colBase = (long)(swz % nCol) * 128;

  // staging geometry: per issue 512 thr x 16B = 8 KB = 64 rows x 8 chunks
  const int srow = tid >> 3;                       // 0..63
  const long scol = (long)(((tid & 7) ^ (srow & 7)) * 8);   // pre-swizzled source
  const __hip_bfloat16* Ab = A  + (rowBase + srow) * (long)K + scol;
  const __hip_bfloat16* Bb = Bt + (colBase + srow) * (long)K + scol;
  char* ldsb = (char*)&lds[0][0];
  const int NT = K >> 6;

  f32x4 acc[4][4] = {};

  auto stageA = [&](int buf, int t, int j) {
    gload_lds16(Ab + ((long)j * 64) * K + (long)t * 64,
                ldsb + buf * 49152 + j * 8192 + wid * 1024);
  };
  auto stageB = [&](int buf, int t, int j) {
    gload_lds16(Bb + ((long)j * 64) * K + (long)t * 64,
                ldsb + buf * 49152 + 32768 + j * 8192 + wid * 1024);
  };
  auto ldA = [&](int buf, int m, int ks) -> bf16x8 {
    const int row = wr * 64 + m * 16 + lr;
    const int c = (ks * 4 + lhi) ^ l7;
    return *(const bf16x8*)(ldsb + buf * 49152 + row * 128 + c * 16);
  };
  auto ldB = [&](int buf, int n, int ks) -> bf16x8 {
    const int row = wc * 64 + n * 16 + lr;
    const int c = (ks * 4 + lhi) ^ l7;
    return *(const bf16x8*)(ldsb + buf * 49152 + 32768 + row * 128 + c * 16);
  };

  // prologue: stage tiles 0 and 1 (6 loads each); wait for tile 0 (leave 6)
#pragma unroll
  for (int j = 0; j < 4; ++j) stageA(0, 0, j);
  stageB(0, 0, 0); stageB(0, 0, 1);
#pragma unroll
  for (int j = 0; j < 4; ++j) stageA(1, 1, j);
  stageB(1, 1, 0); stageB(1, 1, 1);
  asm volatile("s_waitcnt vmcnt(6)" ::: "memory");
  SBAR;

  bf16x8 bv[4][2];

#define PHASE_MFMA(p)                                                     \
    __builtin_amdgcn_s_setprio(1);                                        \
    acc[p][0] = MF(a0, bv[0][0], acc[p][0]);                              \
    acc[p][0] = MF(a1, bv[0][1], acc[p][0]);                              \
    acc[p][1] = MF(a0, bv[1][0], acc[p][1]);                              \
    acc[p][1] = MF(a1, bv[1][1], acc[p][1]);                              \
    acc[p][2] = MF(a0, bv[2][0], acc[p][2]);                              \
    acc[p][2] = MF(a1, bv[2][1], acc[p][2]);                              \
    acc[p][3] = MF(a0, bv[3][0], acc[p][3]);                              \
    acc[p][3] = MF(a1, bv[3][1], acc[p][3]);                              \
    __builtin_amdgcn_s_setprio(0);

  for (int t = 0; t < NT; ++t) {
    const int cur = t % 3;
    const int nxt = (t + 2) % 3;
    const bool st = (t + 2) < NT;

    { // phase 0: all B-frags + A-frag m=0; stage A issues 0,1
#pragma unroll
      for (int n = 0; n < 4; ++n) {
        bv[n][0] = ldB(cur, n, 0);
        bv[n][1] = ldB(cur, n, 1);
      }
      bf16x8 a0 = ldA(cur, 0, 0), a1 = ldA(cur, 0, 1);
      if (st) { stageA(nxt, t + 2, 0); stageA(nxt, t + 2, 1); }
      SBAR;
      PHASE_MFMA(0)
      SBAR;
    }
    { // phase 1: A-frag m=1; stage A issues 2,3
      bf16x8 a0 = ldA(cur, 1, 0), a1 = ldA(cur, 1, 1);
      if (st) { stageA(nxt, t + 2, 2); stageA(nxt, t + 2, 3); }
      SBAR;
      PHASE_MFMA(1)
      SBAR;
    }
    { // phase 2: A-frag m=2; stage B issues 0,1
      bf16x8 a0 = ldA(cur, 2, 0), a1 = ldA(cur, 2, 1);
      if (st) { stageB(nxt, t + 2, 0); stageB(nxt, t + 2, 1); }
      SBAR;
      PHASE_MFMA(2)
      SBAR;
    }
    { // phase 3: A-frag m=3; no stage; then iteration-end counted drain
      bf16x8 a0 = ldA(cur, 3, 0), a1 = ldA(cur, 3, 1);
      SBAR;
      PHASE_MFMA(3)
    }
    if (t + 1 < NT) {
      if (st) asm volatile("s_waitcnt vmcnt(6)" ::: "memory");
      else    asm volatile("s_waitcnt vmcnt(0)" ::: "memory");
      SBAR;   // after this barrier all waves' tile-(t+1) loads have landed
    }
  }
#undef PHASE_MFMA

  // epilogue: C/D layout col = lane&15, row = (lane>>4)*4 + reg
#pragma unroll
  for (int m = 0; m < 4; ++m) {
    const long row0 = rowBase + wr * 64 + m * 16 + lhi * 4;
#pragma unroll
    for (int n = 0; n < 4; ++n) {
      const int col = (int)colBase + wc * 64 + n * 16 + lr;
      const float bvs = (col < Nreal) ? bias[col] : 0.f;
#pragma unroll
      for (int j = 0; j < 4; ++j) {
        float v = acc[m][n][j] + bvs;
        const long row = row0 + j;
        if (EPI == 0) {
          ((__hip_bfloat16*)Cout)[row * N + col] = __float2bfloat16(fmaxf(v, 0.f));
        } else {
          if (col < Nreal)
            ((float*)Cout)[row * Nreal + col] = 1.f / (1.f + expf(-v));
        }
      }
    }
  }
}

// ---------------------------------------------------------------------------
// 2-phase 128x128 gemm (proven) — used for L2 (N=512 needs 256 blocks)
// ---------------------------------------------------------------------------
template <int EPI>
__global__ __launch_bounds__(256)
void gemm_bt(const __hip_bfloat16* __restrict__ A,
             const __hip_bfloat16* __restrict__ Bt,
             const float* __restrict__ bias,
             void* __restrict__ Cout,
             int M, int N, int K, int Nreal)
{
  __shared__ __align__(16) __hip_bfloat16 lds[2][2][128 * 64];  // 64 KB

  const int tid  = threadIdx.x;
  const int wid  = tid >> 6;
  const int lane = tid & 63;
  const int wr = wid >> 1, wc = wid & 1;
  const int lr = lane & 15;
  const int lhi = lane >> 4;
  const long rowBase = (long)blockIdx.x * 128;
  const long colBase = (long)blockIdx.y * 128;

  f32x4 acc[4][4] = {};

  const int srow = tid >> 3;
  const long scol = (long)(((tid & 7) ^ (srow & 7)) * 8);
  const long aBase = (rowBase + srow) * (long)K + scol;
  const long bBase = (colBase + srow) * (long)K + scol;

  const int NT = K >> 6;

  auto STAGE = [&](int buf, int t) {
    const long k0 = (long)t * 64;
    char* la = (char*)&lds[buf][0][0] + wid * 1024;
    char* lb = (char*)&lds[buf][1][0] + wid * 1024;
#pragma unroll
    for (int j = 0; j < 4; ++j) {
      gload_lds16(A  + aBase + (long)j * 32 * K + k0, la + j * 4096);
      gload_lds16(Bt + bBase + (long)j * 32 * K + k0, lb + j * 4096);
    }
  };

  STAGE(0, 0);
  __syncthreads();

  int cur = 0;
  for (int t = 0; t < NT; ++t) {
    if (t + 1 < NT) STAGE(cur ^ 1, t + 1);

    const __hip_bfloat16* la = &lds[cur][0][0];
    const __hip_bfloat16* lb = &lds[cur][1][0];
#pragma unroll
    for (int kk = 0; kk < 2; ++kk) {
      const int ch = ((kk * 4 + lhi) ^ (lane & 7)) * 8;
      bf16x8 af[4], bfv[4];
#pragma unroll
      for (int m = 0; m < 4; ++m)
        af[m] = *reinterpret_cast<const bf16x8*>(&la[(wr * 64 + m * 16 + lr) * 64 + ch]);
#pragma unroll
      for (int n = 0; n < 4; ++n)
        bfv[n] = *reinterpret_cast<const bf16x8*>(&lb[(wc * 64 + n * 16 + lr) * 64 + ch]);
#pragma unroll
      for (int m = 0; m < 4; ++m)
#pragma unroll
        for (int n = 0; n < 4; ++n)
          acc[m][n] = MF(af[m], bfv[n], acc[m][n]);
    }
    __syncthreads();
    cur ^= 1;
  }

#pragma unroll
  for (int m = 0; m < 4; ++m) {
    const long row0 = rowBase + wr * 64 + m * 16 + lhi * 4;
#pragma unroll
    for (int n = 0; n < 4; ++n) {
      const int col = (int)colBase + wc * 64 + n * 16 + lr;
      const float bv = (col < Nreal) ? bias[col] : 0.f;
#pragma unroll
      for (int j = 0; j < 4; ++j) {
        float v = acc[m][n][j] + bv;
        const long row = row0 + j;
        if (EPI == 0) {
          v = fmaxf(v, 0.f);
          ((__hip_bfloat16*)Cout)[row * N + col] = __float2bfloat16(v);
        } else {
          if (col < Nreal)
            ((float*)Cout)[row * Nreal + col] = 1.f / (1.f + expf(-v));
        }
      }
    }
  }
}

// ---------------------------------------------------------------------------
extern "C" void kernel_launch(void* const* d_in, const int* in_sizes, int n_in,
                              void* d_out, int out_size, void* d_ws, size_t ws_size,
                              hipStream_t stream)
{
  const int*   x   = (const int*)  d_in[0];
  const float* emb = (const float*)d_in[1];
  const float* W1  = (const float*)d_in[2];
  const float* b1  = (const float*)d_in[3];
  const float* W2  = (const float*)d_in[4];
  const float* b2  = (const float*)d_in[5];
  const float* W3  = (const float*)d_in[6];
  const float* b3  = (const float*)d_in[7];
  float* out = (float*)d_out;

  char* ws = (char*)d_ws;
  size_t off = 0;
  auto alloc = [&](size_t bytes) { size_t o = off; off = (off + bytes + 255) & ~255ULL; return o; };
  __hip_bfloat16* h   = (__hip_bfloat16*)(ws + alloc((size_t)B_ * IN_PAD * 2));
  __hip_bfloat16* w1t = (__hip_bfloat16*)(ws + alloc((size_t)H1_ * IN_PAD * 2));
  __hip_bfloat16* w2t = (__hip_bfloat16*)(ws + alloc((size_t)H2_ * H1_ * 2));
  __hip_bfloat16* w3t = (__hip_bfloat16*)(ws + alloc((size_t)OUT_PAD * H2_ * 2));
  __hip_bfloat16* h1  = (__hip_bfloat16*)(ws + alloc((size_t)B_ * H1_ * 2));
  __hip_bfloat16* h2  = (__hip_bfloat16*)(ws + alloc((size_t)B_ * H2_ * 2));

  // fused prep: 3 transposes + interact
  prep_kernel<<<5632, 256, 0, stream>>>(x, emb, W1, W2, W3, h, w1t, w2t, w3t);

  // L1: h[8192][2560] @ W1 -> h1 bf16 [8192][1024], relu   (256 blocks)
  gemm8ph<0><<<(B_ / 256) * (H1_ / 128), 512, 0, stream>>>(h, w1t, b1, h1, B_, H1_, IN_PAD, H1_);
  // L2: h1 @ W2 -> h2 bf16 [8192][512], relu               (proven 2-phase)
  gemm_bt<0><<<dim3(B_ / 128, H2_ / 128), 256, 0, stream>>>(h1, w2t, b2, h2, B_, H2_, H1_, H2_);
  // L3: h2 @ W3 -> out fp32 [8192][1000], sigmoid          (256 blocks)
  gemm8ph<1><<<(B_ / 256) * (OUT_PAD / 128), 512, 0, stream>>>(h2, w3t, b3, out, B_, OUT_PAD, H2_, OUT_RAW);
}